// Round 4
// baseline (586.499 us; speedup 1.0000x reference)
//
#include <hip/hip_runtime.h>
#include <cstddef>

#define B   2
#define S   1024
#define PP  1024          // start_pos
#define CTX 2048
#define E   2048
#define H   32
#define KVH 8
#define HD  64
#define GQ  4             // H / KVH
#define NQKV 3072         // E + 2*KVH*HD

typedef short s4v  __attribute__((ext_vector_type(4)));
typedef short s8v  __attribute__((ext_vector_type(8)));
typedef float f4v  __attribute__((ext_vector_type(4)));

__device__ __forceinline__ short f2bf(float f) {   // RNE f32 -> bf16
  union { float f; unsigned u; } v; v.f = f;
  unsigned r = v.u + 0x7fffu + ((v.u >> 16) & 1u);
  return (short)(r >> 16);
}

__device__ __forceinline__ void gl_lds16(const void* g, void* l) {
  __builtin_amdgcn_global_load_lds((const __attribute__((address_space(1))) unsigned*)g,
                                   (__attribute__((address_space(3))) unsigned*)l, 16, 0, 0);
}

// ---------------------------------------------------------------------------
// f32 -> bf16 convert, 8 elems/thread
// ---------------------------------------------------------------------------
__global__ __launch_bounds__(256) void f32_to_bf16(const float* __restrict__ s,
                                                   short* __restrict__ d, int n) {
  int i = (blockIdx.x * 256 + threadIdx.x) * 8;
  if (i >= n) return;
  float4 a = *(const float4*)&s[i];
  float4 b = *(const float4*)&s[i + 4];
  s8v o;
  o[0] = f2bf(a.x); o[1] = f2bf(a.y); o[2] = f2bf(a.z); o[3] = f2bf(a.w);
  o[4] = f2bf(b.x); o[5] = f2bf(b.y); o[6] = f2bf(b.z); o[7] = f2bf(b.w);
  *(s8v*)&d[i] = o;
}

// ---------------------------------------------------------------------------
// bf16 MFMA GEMM (m97 structure + XOR swizzle), C[M,N] f32 = A[M,K] @ B[N,K]^T
// ---------------------------------------------------------------------------
__global__ __launch_bounds__(256) void gemm_bf16(const short* __restrict__ A,
                                                 const short* __restrict__ Bw,
                                                 float* __restrict__ C,
                                                 int M, int N, int K) {
  __shared__ short As[4096];
  __shared__ short Bs[4096];
  const int tid  = threadIdx.x;
  const int wv   = tid >> 6, lane = tid & 63;
  const int wm   = wv & 1, wn = wv >> 1;
  const int n16  = lane & 15, g = lane >> 4;
  const int m0   = blockIdx.y * 128, n0 = blockIdx.x * 128;

  const int s0 = tid, s1 = 256 + tid;
  const int r0 = s0 >> 2, c0 = ((s0 & 3) ^ ((r0 >> 1) & 3)) * 8;
  const int r1 = s1 >> 2, c1 = ((s1 & 3) ^ ((r1 >> 1) & 3)) * 8;
  const short* pA0 = A + (size_t)(m0 + r0) * K + c0;
  const short* pA1 = A + (size_t)(m0 + r1) * K + c1;
  const short* pB0 = Bw + (size_t)(n0 + r0) * K + c0;
  const short* pB1 = Bw + (size_t)(n0 + r1) * K + c1;
  short* lA0 = As + (wv * 64) * 8;
  short* lA1 = As + (256 + wv * 64) * 8;
  short* lB0 = Bs + (wv * 64) * 8;
  short* lB1 = Bs + (256 + wv * 64) * 8;

  const int xv = (g ^ ((n16 >> 1) & 3)) * 8;

  f4v acc[4][4] = {};
  for (int k0 = 0; k0 < K; k0 += 32) {
    __syncthreads();
    gl_lds16(pA0, lA0); gl_lds16(pA1, lA1);
    gl_lds16(pB0, lB0); gl_lds16(pB1, lB1);
    pA0 += 32; pA1 += 32; pB0 += 32; pB1 += 32;
    __syncthreads();

    s8v af[4], bf[4];
#pragma unroll
    for (int mt = 0; mt < 4; mt++)
      af[mt] = *(const s8v*)&As[(wm * 64 + mt * 16 + n16) * 32 + xv];
#pragma unroll
    for (int nt = 0; nt < 4; nt++)
      bf[nt] = *(const s8v*)&Bs[(wn * 64 + nt * 16 + n16) * 32 + xv];
#pragma unroll
    for (int mt = 0; mt < 4; mt++)
#pragma unroll
      for (int nt = 0; nt < 4; nt++)
        acc[mt][nt] = __builtin_amdgcn_mfma_f32_16x16x32_bf16(af[mt], bf[nt], acc[mt][nt], 0, 0, 0);
  }

#pragma unroll
  for (int mt = 0; mt < 4; mt++)
#pragma unroll
    for (int nt = 0; nt < 4; nt++) {
      size_t base = (size_t)(m0 + wm * 64 + mt * 16 + g * 4) * N + n0 + wn * 64 + nt * 16 + n16;
#pragma unroll
      for (int r = 0; r < 4; r++)
        C[base + (size_t)r * N] = acc[mt][nt][r];
    }
}

// ---------------------------------------------------------------------------
// RoPE on q region of qkv buffer (row stride NQKV), in place.
// ---------------------------------------------------------------------------
__global__ __launch_bounds__(256) void rope_q(float* __restrict__ qkv,
                                              const float* __restrict__ cosb,
                                              const float* __restrict__ sinb) {
  int idx = blockIdx.x * 256 + threadIdx.x;   // B*S*H*32
  int d = idx & 31;
  int h = (idx >> 5) & (H - 1);
  int s = (idx >> 10) & (S - 1);
  int b = idx >> 20;
  size_t row = (size_t)b * S + s;
  float c = cosb[row * HD + d];
  float sn = sinb[row * HD + d];
  float* qp = qkv + row * NQKV + h * 64;
  float q1 = qp[d], q2 = qp[d + 32];
  qp[d] = q1 * c - q2 * sn;
  qp[d + 32] = q2 * c + q1 * sn;
}

// ---------------------------------------------------------------------------
// RoPE on k region of qkv + scatter (bf16) into keys at pos PP+s.
// ---------------------------------------------------------------------------
__global__ __launch_bounds__(256) void rope_k(const float* __restrict__ qkv,
                                              const float* __restrict__ cosb,
                                              const float* __restrict__ sinb,
                                              short* __restrict__ keys) {
  int idx = blockIdx.x * 256 + threadIdx.x;   // B*S*KVH*32
  int d = idx & 31;
  int kv = (idx >> 5) & (KVH - 1);
  int s = (idx >> 8) & (S - 1);
  int b = idx >> 18;
  size_t row = (size_t)b * S + s;
  float c = cosb[row * HD + d];
  float sn = sinb[row * HD + d];
  const float* base = qkv + row * NQKV;
  float k1 = base[E + kv * 64 + d], k2 = base[E + kv * 64 + d + 32];
  size_t drow = (((size_t)b * KVH + kv) * CTX + PP + s) * HD;
  keys[drow + d]      = f2bf(k1 * c - k2 * sn);
  keys[drow + d + 32] = f2bf(k2 * c + k1 * sn);
}

// ---------------------------------------------------------------------------
// cache_k f32 positions [0,PP) -> bf16 keys (same [b][kv][ctx][hd] layout)
// ---------------------------------------------------------------------------
__global__ __launch_bounds__(256) void copy_cache_k(const float* __restrict__ ck,
                                                    short* __restrict__ keys) {
  int idx = blockIdx.x * 256 + threadIdx.x;   // B*KVH*PP*HD/8
  int bkv = idx >> 13;
  int rem = idx & 8191;
  size_t off = (size_t)bkv * (CTX * HD) + (size_t)rem * 8;
  float4 a = *(const float4*)&ck[off];
  float4 b = *(const float4*)&ck[off + 4];
  s8v o;
  o[0]=f2bf(a.x); o[1]=f2bf(a.y); o[2]=f2bf(a.z); o[3]=f2bf(a.w);
  o[4]=f2bf(b.x); o[5]=f2bf(b.y); o[6]=f2bf(b.z); o[7]=f2bf(b.w);
  *(s8v*)&keys[off] = o;
}

// ---------------------------------------------------------------------------
// V transpose kernels -> valsT[(b*KVH+kv)*HD + d][CTX] bf16
// ---------------------------------------------------------------------------
__global__ __launch_bounds__(256) void vT_old(const float* __restrict__ cv,
                                              short* __restrict__ vt) {
  __shared__ short Ts[64][72];
  const int blk = blockIdx.x;               // B*KVH*(PP/64) = 256
  const int bkv = blk >> 4;
  const int p0  = (blk & 15) * 64;
  const int t = threadIdx.x;
  const float* src = cv + (size_t)bkv * CTX * HD + (size_t)p0 * HD;
  {
    int dq = t & 15, kb = t >> 4;
    float4 vv[4];
#pragma unroll
    for (int i = 0; i < 4; i++)
      vv[i] = *(const float4*)&src[(size_t)(kb * 4 + i) * HD + dq * 4];
#pragma unroll
    for (int j = 0; j < 4; j++) {
      s4v p;
      p[0]=f2bf(((const float*)&vv[0])[j]); p[1]=f2bf(((const float*)&vv[1])[j]);
      p[2]=f2bf(((const float*)&vv[2])[j]); p[3]=f2bf(((const float*)&vv[3])[j]);
      *(s4v*)&Ts[dq * 4 + j][kb * 4] = p;
    }
  }
  __syncthreads();
  {
    int d = t >> 2, c = t & 3;
    s8v a  = *(const s8v*)&Ts[d][c * 16];
    s8v b2 = *(const s8v*)&Ts[d][c * 16 + 8];
    short* dst = vt + ((size_t)bkv * HD + d) * CTX + p0 + c * 16;
    *(s8v*)&dst[0] = a;
    *(s8v*)&dst[8] = b2;
  }
}

__global__ __launch_bounds__(256) void vT_new(const float* __restrict__ qkv,
                                              short* __restrict__ vt) {
  __shared__ short Ts[64][72];
  const int blk = blockIdx.x;               // B*KVH*(S/64) = 256
  const int bkv = blk >> 4;
  const int b = bkv >> 3, kv = bkv & 7;
  const int s0 = (blk & 15) * 64;
  const int t = threadIdx.x;
  const float* src = qkv + ((size_t)b * S + s0) * NQKV + E + 512 + kv * 64;
  {
    int dq = t & 15, kb = t >> 4;
    float4 vv[4];
#pragma unroll
    for (int i = 0; i < 4; i++)
      vv[i] = *(const float4*)&src[(size_t)(kb * 4 + i) * NQKV + dq * 4];
#pragma unroll
    for (int j = 0; j < 4; j++) {
      s4v p;
      p[0]=f2bf(((const float*)&vv[0])[j]); p[1]=f2bf(((const float*)&vv[1])[j]);
      p[2]=f2bf(((const float*)&vv[2])[j]); p[3]=f2bf(((const float*)&vv[3])[j]);
      *(s4v*)&Ts[dq * 4 + j][kb * 4] = p;
    }
  }
  __syncthreads();
  {
    int d = t >> 2, c = t & 3;
    s8v a  = *(const s8v*)&Ts[d][c * 16];
    s8v b2 = *(const s8v*)&Ts[d][c * 16 + 8];
    short* dst = vt + ((size_t)bkv * HD + d) * CTX + PP + s0 + c * 16;
    *(s8v*)&dst[0] = a;
    *(s8v*)&dst[8] = b2;
  }
}

// ---------------------------------------------------------------------------
// LDS-free MFMA flash attention.
// QK: A = K rows direct from global (natural slot map, dims g*8+j),
//     B = Q frags in registers. S^T in C-layout: lane (g,n) reg r = key
//     st*16+g*4+r, query n.
// PV: g-dependent slot map k(g,j) = (j>>2)*16 + g*4 + (j&3). B = bf16(P^T)
//     straight from the sc registers; A = V^T frags from the pre-transposed
//     global valsT (two 8-B loads per frag). O accumulates as O^T: query =
//     col = lane's own n -> alpha rescale + 1/l normalize need no shuffles.
// No LDS, no barriers: waves independent; each wave clips its own K-range.
// ---------------------------------------------------------------------------
__global__ __launch_bounds__(256) void attn_mfma(const float* __restrict__ qkv,
                                                 const short* __restrict__ keys,
                                                 const short* __restrict__ valsT,
                                                 short* __restrict__ attn) {
  const int sblk = 15 - (blockIdx.x & 15);     // long blocks first
  const int h    = (blockIdx.x >> 4) & (H - 1);
  const int b    = blockIdx.x >> 9;
  const int kv   = h >> 2;
  const int sq0  = sblk * 64;

  const int tid  = threadIdx.x;
  const int w    = tid >> 6;
  const int lane = tid & 63;
  const int n    = lane & 15;
  const int g    = lane >> 4;

  const short* kbase = keys  + ((size_t)b * KVH + kv) * CTX * HD;
  const short* vtb   = valsT + ((size_t)b * KVH + kv) * (size_t)HD * CTX;

  // Q fragments (fp32 from qkv, fold 1/sqrt(HD)); dims g*8+j (lo), 32+g*8+j (hi)
  union { s4v h4[2]; s8v v; } qlo, qhi;
  {
    const float* qrow = qkv + ((size_t)b * S + sq0 + w * 16 + n) * NQKV + h * 64;
    float4 f0 = *(const float4*)&qrow[g * 8];
    float4 f1 = *(const float4*)&qrow[g * 8 + 4];
    float4 f2 = *(const float4*)&qrow[32 + g * 8];
    float4 f3 = *(const float4*)&qrow[32 + g * 8 + 4];
    s4v a, c;
    a[0]=f2bf(f0.x*0.125f); a[1]=f2bf(f0.y*0.125f); a[2]=f2bf(f0.z*0.125f); a[3]=f2bf(f0.w*0.125f);
    qlo.h4[0]=a;
    a[0]=f2bf(f1.x*0.125f); a[1]=f2bf(f1.y*0.125f); a[2]=f2bf(f1.z*0.125f); a[3]=f2bf(f1.w*0.125f);
    qlo.h4[1]=a;
    c[0]=f2bf(f2.x*0.125f); c[1]=f2bf(f2.y*0.125f); c[2]=f2bf(f2.z*0.125f); c[3]=f2bf(f2.w*0.125f);
    qhi.h4[0]=c;
    c[0]=f2bf(f3.x*0.125f); c[1]=f2bf(f3.y*0.125f); c[2]=f2bf(f3.z*0.125f); c[3]=f2bf(f3.w*0.125f);
    qhi.h4[1]=c;
  }

  f4v O[4] = {{0,0,0,0},{0,0,0,0},{0,0,0,0},{0,0,0,0}};
  float m = -3e38f, l = 0.f;
  const int qp     = PP + sq0 + w * 16 + n;    // this lane's query position
  const int qmin_w = PP + sq0 + w * 16;
  const int kend_w = qmin_w + 16;              // wave-private K-range bound

  for (int k0 = 0; k0 < kend_w; k0 += 64) {
    // ---- QK: K-frags direct from global ----
    f4v sc[4];
#pragma unroll
    for (int st = 0; st < 4; st++) {
      const short* kr = kbase + (size_t)(k0 + st * 16 + n) * HD + g * 8;
      s8v alo = *(const s8v*)kr;
      s8v ahi = *(const s8v*)(kr + 32);
      f4v z = {0.f, 0.f, 0.f, 0.f};
      z = __builtin_amdgcn_mfma_f32_16x16x32_bf16(alo, qlo.v, z, 0, 0, 0);
      sc[st] = __builtin_amdgcn_mfma_f32_16x16x32_bf16(ahi, qhi.v, z, 0, 0, 0);
    }

    // ---- causal mask near diagonal ----
    if (k0 + 63 > qmin_w) {
#pragma unroll
      for (int st = 0; st < 4; st++)
#pragma unroll
        for (int r = 0; r < 4; r++) {
          int kpos = k0 + st * 16 + g * 4 + r;
          if (kpos > qp) sc[st][r] = -3e38f;
        }
    }

    // ---- online softmax (per query = col n; lanes g share via xor 16/32) ----
    float ml = sc[0][0];
#pragma unroll
    for (int st = 0; st < 4; st++)
#pragma unroll
      for (int r = 0; r < 4; r++) ml = fmaxf(ml, sc[st][r]);
    ml = fmaxf(ml, __shfl_xor(ml, 16));
    ml = fmaxf(ml, __shfl_xor(ml, 32));
    float mn = fmaxf(m, ml);
    float alpha = __expf(m - mn);
    m = mn;
    float ls = 0.f;
    union { s4v h4[2]; s8v v; } pb0, pb1;
#pragma unroll
    for (int st = 0; st < 4; st++) {
      s4v pw;
#pragma unroll
      for (int r = 0; r < 4; r++) {
        float e = __expf(sc[st][r] - m);
        ls += e;
        pw[r] = f2bf(e);
      }
      if (st < 2) pb0.h4[st] = pw; else pb1.h4[st - 2] = pw;
    }
    ls += __shfl_xor(ls, 16);
    ls += __shfl_xor(ls, 32);
    l = l * alpha + ls;

    // ---- rescale O (query = lane's own n) ----
#pragma unroll
    for (int dg = 0; dg < 4; dg++) {
      O[dg][0] *= alpha; O[dg][1] *= alpha; O[dg][2] *= alpha; O[dg][3] *= alpha;
    }

    // ---- PV: A = V^T frags from global, B = P^T in registers ----
#pragma unroll
    for (int dg = 0; dg < 4; dg++) {
      const short* vr = vtb + (size_t)(dg * 16 + n) * CTX + k0 + g * 4;
      union { s4v h4[2]; s8v v; } va, vb;
      va.h4[0] = *(const s4v*)vr;
      va.h4[1] = *(const s4v*)(vr + 16);
      vb.h4[0] = *(const s4v*)(vr + 32);
      vb.h4[1] = *(const s4v*)(vr + 48);
      O[dg] = __builtin_amdgcn_mfma_f32_16x16x32_bf16(va.v, pb0.v, O[dg], 0, 0, 0);
      O[dg] = __builtin_amdgcn_mfma_f32_16x16x32_bf16(vb.v, pb1.v, O[dg], 0, 0, 0);
    }
  }

  // ---- epilogue: O^T lane (g,n) reg r = dim dg*16+g*4+r, query n ----
  const float rl = 1.f / l;
  short* orow = attn + ((size_t)b * S + sq0 + w * 16 + n) * E + h * 64;
#pragma unroll
  for (int dg = 0; dg < 4; dg++) {
    s4v o;
    o[0] = f2bf(O[dg][0] * rl); o[1] = f2bf(O[dg][1] * rl);
    o[2] = f2bf(O[dg][2] * rl); o[3] = f2bf(O[dg][3] * rl);
    *(s4v*)&orow[dg * 16 + g * 4] = o;
  }
}

// ---------------------------------------------------------------------------
extern "C" void kernel_launch(void* const* d_in, const int* in_sizes, int n_in,
                              void* d_out, int out_size, void* d_ws, size_t ws_size,
                              hipStream_t stream) {
  const float* x       = (const float*)d_in[0];
  const float* cosb    = (const float*)d_in[1];
  const float* sinb    = (const float*)d_in[2];
  const float* cache_k = (const float*)d_in[4];
  const float* cache_v = (const float*)d_in[5];
  const float* Wq      = (const float*)d_in[6];
  const float* Wk      = (const float*)d_in[7];
  const float* Wv      = (const float*)d_in[8];
  const float* Wo      = (const float*)d_in[9];
  float* out = (float*)d_out;

  short* xb    = (short*)d_ws;                 // 4194304 bf16
  short* wqkv  = xb + 4194304;                 // 6291456 bf16
  short* wob   = wqkv + 6291456;               // 4194304 bf16
  short* keysb = wob + 4194304;                // 2097152 bf16
  short* valsT = keysb + 2097152;              // 2097152 bf16 (V^T: [bkv*HD+d][CTX])
  short* aout  = valsT + 2097152;              // 4194304 bf16
  float* qkv   = (float*)(aout + 4194304);     // 6291456 f32; total ~68 MB

  dim3 blk(256);

  f32_to_bf16<<<2048, blk, 0, stream>>>(x,  xb,   4194304);
  f32_to_bf16<<<2048, blk, 0, stream>>>(Wq, wqkv, 4194304);
  f32_to_bf16<<<512,  blk, 0, stream>>>(Wk, wqkv + 4194304, 1048576);
  f32_to_bf16<<<512,  blk, 0, stream>>>(Wv, wqkv + 5242880, 1048576);
  f32_to_bf16<<<2048, blk, 0, stream>>>(Wo, wob, 4194304);

  // old-cache halves (independent of x)
  copy_cache_k<<<512, blk, 0, stream>>>(cache_k, keysb);
  vT_old<<<256, blk, 0, stream>>>(cache_v, valsT);

  // fused QKV projection: [2048,2048] @ [3072,2048]^T
  gemm_bf16<<<dim3(NQKV / 128, (B * S) / 128), blk, 0, stream>>>(xb, wqkv, qkv, B * S, NQKV, E);

  // RoPE + new KV halves
  rope_q<<<(B * S * H * 32) / 256, blk, 0, stream>>>(qkv, cosb, sinb);
  rope_k<<<(B * S * KVH * 32) / 256, blk, 0, stream>>>(qkv, cosb, sinb, keysb);
  vT_new<<<256, blk, 0, stream>>>(qkv, valsT);

  // attention -> bf16 (B,S,E)
  attn_mfma<<<B * H * (S / 64), blk, 0, stream>>>(qkv, keysb, valsT, aout);

  // output projection -> f32 out
  gemm_bf16<<<dim3(E / 128, (B * S) / 128), blk, 0, stream>>>(aout, wob, out, B * S, E, E);
}

// Round 6
// 333.156 us; speedup vs baseline: 1.7604x; 1.7604x over previous
//
#include <hip/hip_runtime.h>
#include <cstddef>

#define B   2
#define S   1024
#define PP  1024          // start_pos
#define CTX 2048
#define E   2048
#define H   32
#define KVH 8
#define HD  64
#define GQ  4             // H / KVH
#define NQKV 3072         // E + 2*KVH*HD

typedef short s4v  __attribute__((ext_vector_type(4)));
typedef short s8v  __attribute__((ext_vector_type(8)));
typedef float f4v  __attribute__((ext_vector_type(4)));

__device__ __forceinline__ short f2bf(float f) {   // RNE f32 -> bf16
  union { float f; unsigned u; } v; v.f = f;
  unsigned r = v.u + 0x7fffu + ((v.u >> 16) & 1u);
  return (short)(r >> 16);
}

__device__ __forceinline__ void gl_lds16(const void* g, void* l) {
  __builtin_amdgcn_global_load_lds((const __attribute__((address_space(1))) unsigned*)g,
                                   (__attribute__((address_space(3))) unsigned*)l, 16, 0, 0);
}

// ---------------------------------------------------------------------------
// f32 -> bf16 convert, 8 elems/thread
// ---------------------------------------------------------------------------
__global__ __launch_bounds__(256) void f32_to_bf16(const float* __restrict__ s,
                                                   short* __restrict__ d, int n) {
  int i = (blockIdx.x * 256 + threadIdx.x) * 8;
  if (i >= n) return;
  float4 a = *(const float4*)&s[i];
  float4 b = *(const float4*)&s[i + 4];
  s8v o;
  o[0] = f2bf(a.x); o[1] = f2bf(a.y); o[2] = f2bf(a.z); o[3] = f2bf(a.w);
  o[4] = f2bf(b.x); o[5] = f2bf(b.y); o[6] = f2bf(b.z); o[7] = f2bf(b.w);
  *(s8v*)&d[i] = o;
}

__global__ __launch_bounds__(256) void zero_f32(float4* __restrict__ p, int n4) {
  int i = blockIdx.x * 256 + threadIdx.x;
  if (i < n4) p[i] = make_float4(0.f, 0.f, 0.f, 0.f);
}

// ---------------------------------------------------------------------------
// bf16 MFMA GEMM, split-K=2 (blockIdx.z), atomic f32 accumulate into C.
// m97 structure + XOR swizzle. C must be zeroed before launch.
// ---------------------------------------------------------------------------
__global__ __launch_bounds__(256) void gemm_bf16_sk(const short* __restrict__ A,
                                                    const short* __restrict__ Bw,
                                                    float* __restrict__ C,
                                                    int M, int N, int K) {
  __shared__ short As[4096];
  __shared__ short Bs[4096];
  const int tid  = threadIdx.x;
  const int wv   = tid >> 6, lane = tid & 63;
  const int wm   = wv & 1, wn = wv >> 1;
  const int n16  = lane & 15, g = lane >> 4;
  const int m0   = blockIdx.y * 128, n0 = blockIdx.x * 128;
  const int kh   = K >> 1;
  const int kbeg = blockIdx.z * kh;

  const int s0 = tid, s1 = 256 + tid;
  const int r0 = s0 >> 2, c0 = ((s0 & 3) ^ ((r0 >> 1) & 3)) * 8;
  const int r1 = s1 >> 2, c1 = ((s1 & 3) ^ ((r1 >> 1) & 3)) * 8;
  const short* pA0 = A + (size_t)(m0 + r0) * K + kbeg + c0;
  const short* pA1 = A + (size_t)(m0 + r1) * K + kbeg + c1;
  const short* pB0 = Bw + (size_t)(n0 + r0) * K + kbeg + c0;
  const short* pB1 = Bw + (size_t)(n0 + r1) * K + kbeg + c1;
  short* lA0 = As + (wv * 64) * 8;
  short* lA1 = As + (256 + wv * 64) * 8;
  short* lB0 = Bs + (wv * 64) * 8;
  short* lB1 = Bs + (256 + wv * 64) * 8;

  const int xv = (g ^ ((n16 >> 1) & 3)) * 8;

  f4v acc[4][4] = {};
  for (int k0 = 0; k0 < kh; k0 += 32) {
    __syncthreads();
    gl_lds16(pA0, lA0); gl_lds16(pA1, lA1);
    gl_lds16(pB0, lB0); gl_lds16(pB1, lB1);
    pA0 += 32; pA1 += 32; pB0 += 32; pB1 += 32;
    __syncthreads();

    s8v af[4], bf[4];
#pragma unroll
    for (int mt = 0; mt < 4; mt++)
      af[mt] = *(const s8v*)&As[(wm * 64 + mt * 16 + n16) * 32 + xv];
#pragma unroll
    for (int nt = 0; nt < 4; nt++)
      bf[nt] = *(const s8v*)&Bs[(wn * 64 + nt * 16 + n16) * 32 + xv];
#pragma unroll
    for (int mt = 0; mt < 4; mt++)
#pragma unroll
      for (int nt = 0; nt < 4; nt++)
        acc[mt][nt] = __builtin_amdgcn_mfma_f32_16x16x32_bf16(af[mt], bf[nt], acc[mt][nt], 0, 0, 0);
  }

#pragma unroll
  for (int mt = 0; mt < 4; mt++)
#pragma unroll
    for (int nt = 0; nt < 4; nt++) {
      size_t base = (size_t)(m0 + wm * 64 + mt * 16 + g * 4) * N + n0 + wn * 64 + nt * 16 + n16;
#pragma unroll
      for (int r = 0; r < 4; r++)
        unsafeAtomicAdd(&C[base + (size_t)r * N], acc[mt][nt][r]);
    }
}

// ---------------------------------------------------------------------------
// RoPE on k region of qkv + scatter (bf16) into keys at pos PP+s.
// ---------------------------------------------------------------------------
__global__ __launch_bounds__(256) void rope_k(const float* __restrict__ qkv,
                                              const float* __restrict__ cosb,
                                              const float* __restrict__ sinb,
                                              short* __restrict__ keys) {
  int idx = blockIdx.x * 256 + threadIdx.x;   // B*S*KVH*32
  int d = idx & 31;
  int kv = (idx >> 5) & (KVH - 1);
  int s = (idx >> 8) & (S - 1);
  int b = idx >> 18;
  size_t row = (size_t)b * S + s;
  float c = cosb[row * HD + d];
  float sn = sinb[row * HD + d];
  const float* base = qkv + row * NQKV;
  float k1 = base[E + kv * 64 + d], k2 = base[E + kv * 64 + d + 32];
  size_t drow = (((size_t)b * KVH + kv) * CTX + PP + s) * HD;
  keys[drow + d]      = f2bf(k1 * c - k2 * sn);
  keys[drow + d + 32] = f2bf(k2 * c + k1 * sn);
}

// ---------------------------------------------------------------------------
// cache_k f32 positions [0,PP) -> bf16 keys
// ---------------------------------------------------------------------------
__global__ __launch_bounds__(256) void copy_cache_k(const float* __restrict__ ck,
                                                    short* __restrict__ keys) {
  int idx = blockIdx.x * 256 + threadIdx.x;   // B*KVH*PP*HD/8
  int bkv = idx >> 13;
  int rem = idx & 8191;
  size_t off = (size_t)bkv * (CTX * HD) + (size_t)rem * 8;
  float4 a = *(const float4*)&ck[off];
  float4 b = *(const float4*)&ck[off + 4];
  s8v o;
  o[0]=f2bf(a.x); o[1]=f2bf(a.y); o[2]=f2bf(a.z); o[3]=f2bf(a.w);
  o[4]=f2bf(b.x); o[5]=f2bf(b.y); o[6]=f2bf(b.z); o[7]=f2bf(b.w);
  *(s8v*)&keys[off] = o;
}

// ---------------------------------------------------------------------------
// V transpose -> valsT[(b*KVH+kv)*HD + d][CTX] bf16, with key order PERMUTED
// within each 64-key block: key (b4*16 + g*4 + r) at pos (g*8 + b4*4 + r)
// per 32-half, so a PV A-frag is one contiguous 16-B read at col g*8.
// ---------------------------------------------------------------------------
__global__ __launch_bounds__(256) void vT_old(const float* __restrict__ cv,
                                              short* __restrict__ vt) {
  __shared__ short Ts[64][72];
  const int blk = blockIdx.x;               // B*KVH*(PP/64) = 256
  const int bkv = blk >> 4;
  const int p0  = (blk & 15) * 64;
  const int t = threadIdx.x;
  const float* src = cv + (size_t)bkv * CTX * HD + (size_t)p0 * HD;
  {
    int dq = t & 15, kb = t >> 4;
    float4 vv[4];
#pragma unroll
    for (int i = 0; i < 4; i++)
      vv[i] = *(const float4*)&src[(size_t)(kb * 4 + i) * HD + dq * 4];
#pragma unroll
    for (int j = 0; j < 4; j++) {
      s4v p;
      p[0]=f2bf(((const float*)&vv[0])[j]); p[1]=f2bf(((const float*)&vv[1])[j]);
      p[2]=f2bf(((const float*)&vv[2])[j]); p[3]=f2bf(((const float*)&vv[3])[j]);
      *(s4v*)&Ts[dq * 4 + j][kb * 4] = p;
    }
  }
  __syncthreads();
  {
    int d = t >> 2, c = t & 3;   // c: group of 16 keys
    short* dst = vt + ((size_t)bkv * HD + d) * CTX + p0 + (c >> 1) * 32 + (c & 1) * 4;
#pragma unroll
    for (int j = 0; j < 4; j++) {
      s4v q4 = *(const s4v*)&Ts[d][c * 16 + j * 4];
      *(s4v*)&dst[j * 8] = q4;
    }
  }
}

__global__ __launch_bounds__(256) void vT_new(const float* __restrict__ qkv,
                                              short* __restrict__ vt) {
  __shared__ short Ts[64][72];
  const int blk = blockIdx.x;               // B*KVH*(S/64) = 256
  const int bkv = blk >> 4;
  const int b = bkv >> 3, kv = bkv & 7;
  const int s0 = (blk & 15) * 64;
  const int t = threadIdx.x;
  const float* src = qkv + ((size_t)b * S + s0) * NQKV + E + 512 + kv * 64;
  {
    int dq = t & 15, kb = t >> 4;
    float4 vv[4];
#pragma unroll
    for (int i = 0; i < 4; i++)
      vv[i] = *(const float4*)&src[(size_t)(kb * 4 + i) * NQKV + dq * 4];
#pragma unroll
    for (int j = 0; j < 4; j++) {
      s4v p;
      p[0]=f2bf(((const float*)&vv[0])[j]); p[1]=f2bf(((const float*)&vv[1])[j]);
      p[2]=f2bf(((const float*)&vv[2])[j]); p[3]=f2bf(((const float*)&vv[3])[j]);
      *(s4v*)&Ts[dq * 4 + j][kb * 4] = p;
    }
  }
  __syncthreads();
  {
    int d = t >> 2, c = t & 3;
    short* dst = vt + ((size_t)bkv * HD + d) * CTX + PP + s0 + (c >> 1) * 32 + (c & 1) * 4;
#pragma unroll
    for (int j = 0; j < 4; j++) {
      s4v q4 = *(const s4v*)&Ts[d][c * 16 + j * 4];
      *(s4v*)&dst[j * 8] = q4;
    }
  }
}

// ---------------------------------------------------------------------------
// MFMA flash attention, fixed-max softmax (exp2, M=16), LDS-staged K & V^T,
// register P^T (PV B-operand direct from QK output), RoPE folded into Q load.
// Per tile: 2 barriers + coop stage + 16 ds_read + 16 exp2 + 16 MFMA.
// No cross-lane ops in the K-loop; l reduced once at the end.
// ---------------------------------------------------------------------------
__global__ __launch_bounds__(256) void attn_mfma(const float* __restrict__ qkv,
                                                 const float* __restrict__ cosb,
                                                 const float* __restrict__ sinb,
                                                 const short* __restrict__ keys,
                                                 const short* __restrict__ valsT,
                                                 short* __restrict__ attn) {
  __shared__ short Ks[64 * 72];    // K tile [key][dim], stride 72
  __shared__ short VTs[64 * 72];   // V^T tile [dim][permuted key], stride 72

  const int sblk = 15 - (blockIdx.x & 15);     // long blocks first
  const int h    = (blockIdx.x >> 4) & (H - 1);
  const int b    = blockIdx.x >> 9;
  const int kv   = h >> 2;
  const int sq0  = sblk * 64;
  const int kend = PP + sq0 + 64;

  const int tid  = threadIdx.x;
  const int w    = tid >> 6;
  const int lane = tid & 63;
  const int n    = lane & 15;
  const int g    = lane >> 4;

  const short* kbase = keys  + ((size_t)b * KVH + kv) * CTX * HD;
  const short* vtb   = valsT + ((size_t)b * KVH + kv) * (size_t)HD * CTX;

  // ---- Q frags with fused RoPE; scale = 0.125 * log2(e) (exp2 softmax) ----
  union { s4v h4[2]; s8v v; } qlo, qhi;
  {
    const size_t row = (size_t)b * S + sq0 + w * 16 + n;
    const float* qrow = qkv + row * NQKV + h * 64;
    const float* crow = cosb + row * HD;
    const float* srow = sinb + row * HD;
    const float SC = 0.18033688011112042f;   // 0.125 * log2(e)
    float4 f0 = *(const float4*)&qrow[g * 8];
    float4 f1 = *(const float4*)&qrow[g * 8 + 4];
    float4 f2 = *(const float4*)&qrow[32 + g * 8];
    float4 f3 = *(const float4*)&qrow[32 + g * 8 + 4];
    float4 c0 = *(const float4*)&crow[g * 8];
    float4 c1 = *(const float4*)&crow[g * 8 + 4];
    float4 sn0 = *(const float4*)&srow[g * 8];
    float4 sn1 = *(const float4*)&srow[g * 8 + 4];
    s4v a, c;
    a[0] = f2bf((f0.x * c0.x - f2.x * sn0.x) * SC);
    a[1] = f2bf((f0.y * c0.y - f2.y * sn0.y) * SC);
    a[2] = f2bf((f0.z * c0.z - f2.z * sn0.z) * SC);
    a[3] = f2bf((f0.w * c0.w - f2.w * sn0.w) * SC);
    qlo.h4[0] = a;
    a[0] = f2bf((f1.x * c1.x - f3.x * sn1.x) * SC);
    a[1] = f2bf((f1.y * c1.y - f3.y * sn1.y) * SC);
    a[2] = f2bf((f1.z * c1.z - f3.z * sn1.z) * SC);
    a[3] = f2bf((f1.w * c1.w - f3.w * sn1.w) * SC);
    qlo.h4[1] = a;
    c[0] = f2bf((f2.x * c0.x + f0.x * sn0.x) * SC);
    c[1] = f2bf((f2.y * c0.y + f0.y * sn0.y) * SC);
    c[2] = f2bf((f2.z * c0.z + f0.z * sn0.z) * SC);
    c[3] = f2bf((f2.w * c0.w + f0.w * sn0.w) * SC);
    qhi.h4[0] = c;
    c[0] = f2bf((f3.x * c1.x + f1.x * sn1.x) * SC);
    c[1] = f2bf((f3.y * c1.y + f1.y * sn1.y) * SC);
    c[2] = f2bf((f3.z * c1.z + f1.z * sn1.z) * SC);
    c[3] = f2bf((f3.w * c1.w + f1.w * sn1.w) * SC);
    qhi.h4[1] = c;
  }

  f4v O[4] = {{0,0,0,0},{0,0,0,0},{0,0,0,0},{0,0,0,0}};
  float l = 0.f;
  const int qp     = PP + sq0 + w * 16 + n;    // this lane's query position
  const int qmin_w = PP + sq0 + w * 16;        // wave's min query position

  // staging assignment: thread -> (row, 16-short col chunk)
  const int srow = tid >> 2;
  const int scol = (tid & 3) * 16;
  const short* kst = kbase + (size_t)srow * HD + scol;
  const short* vst = vtb + (size_t)srow * CTX + scol;
  short* ksd = &Ks[srow * 72 + scol];
  short* vsd = &VTs[srow * 72 + scol];

  for (int k0 = 0; k0 < kend; k0 += 64) {
    __syncthreads();
    { // cooperative stage: 32 B K + 32 B V^T per thread
      const short* kp = kst + (size_t)k0 * HD;
      s8v a0 = *(const s8v*)kp;
      s8v a1 = *(const s8v*)(kp + 8);
      const short* vp = vst + k0;
      s8v b0 = *(const s8v*)vp;
      s8v b1 = *(const s8v*)(vp + 8);
      *(s8v*)ksd = a0; *(s8v*)(ksd + 8) = a1;
      *(s8v*)vsd = b0; *(s8v*)(vsd + 8) = b1;
    }
    __syncthreads();

    if (k0 >= qmin_w + 16) continue;   // wave's K-range done (barriers stay aligned)

    // ---- S^T = K_tile @ Q^T (scores in log2 units) ----
    f4v sc[4];
#pragma unroll
    for (int st = 0; st < 4; st++) {
      s8v alo = *(const s8v*)&Ks[(st * 16 + n) * 72 + g * 8];
      s8v ahi = *(const s8v*)&Ks[(st * 16 + n) * 72 + 32 + g * 8];
      f4v z = {0.f, 0.f, 0.f, 0.f};
      z = __builtin_amdgcn_mfma_f32_16x16x32_bf16(alo, qlo.v, z, 0, 0, 0);
      sc[st] = __builtin_amdgcn_mfma_f32_16x16x32_bf16(ahi, qhi.v, z, 0, 0, 0);
    }

    // ---- causal mask near diagonal ----
    if (k0 + 63 > qmin_w) {
#pragma unroll
      for (int st = 0; st < 4; st++)
#pragma unroll
        for (int r = 0; r < 4; r++) {
          int kpos = k0 + st * 16 + g * 4 + r;
          if (kpos > qp) sc[st][r] = -3e38f;
        }
    }

    // ---- fixed-max exp2; P^T packed straight into PV B-operand regs ----
    union { s4v h4[2]; s8v v; } pb0, pb1;
#pragma unroll
    for (int st = 0; st < 4; st++) {
      s4v pw;
#pragma unroll
      for (int r = 0; r < 4; r++) {
        float e = __builtin_amdgcn_exp2f(sc[st][r] - 16.f);
        l += e;
        pw[r] = f2bf(e);
      }
      if (st < 2) pb0.h4[st] = pw; else pb1.h4[st - 2] = pw;
    }

    // ---- O^T += V^T @ P : A-frags one b128 each from permuted VTs ----
#pragma unroll
    for (int dg = 0; dg < 4; dg++) {
      const short* vr = &VTs[(dg * 16 + n) * 72];
      s8v va = *(const s8v*)(vr + g * 8);
      s8v vb = *(const s8v*)(vr + 32 + g * 8);
      O[dg] = __builtin_amdgcn_mfma_f32_16x16x32_bf16(va, pb0.v, O[dg], 0, 0, 0);
      O[dg] = __builtin_amdgcn_mfma_f32_16x16x32_bf16(vb, pb1.v, O[dg], 0, 0, 0);
    }
  }

  // ---- reduce l across the 4 g-lanes of each query, normalize, store ----
  l += __shfl_xor(l, 16);
  l += __shfl_xor(l, 32);
  const float rl = 1.f / l;
  short* orow = attn + ((size_t)b * S + sq0 + w * 16 + n) * E + h * 64;
#pragma unroll
  for (int dg = 0; dg < 4; dg++) {
    s4v o;
    o[0] = f2bf(O[dg][0] * rl); o[1] = f2bf(O[dg][1] * rl);
    o[2] = f2bf(O[dg][2] * rl); o[3] = f2bf(O[dg][3] * rl);
    *(s4v*)&orow[dg * 16 + g * 4] = o;
  }
}

// ---------------------------------------------------------------------------
extern "C" void kernel_launch(void* const* d_in, const int* in_sizes, int n_in,
                              void* d_out, int out_size, void* d_ws, size_t ws_size,
                              hipStream_t stream) {
  const float* x       = (const float*)d_in[0];
  const float* cosb    = (const float*)d_in[1];
  const float* sinb    = (const float*)d_in[2];
  const float* cache_k = (const float*)d_in[4];
  const float* cache_v = (const float*)d_in[5];
  const float* Wq      = (const float*)d_in[6];
  const float* Wk      = (const float*)d_in[7];
  const float* Wv      = (const float*)d_in[8];
  const float* Wo      = (const float*)d_in[9];
  float* out = (float*)d_out;

  short* xb    = (short*)d_ws;                 // 4194304 bf16
  short* wqkv  = xb + 4194304;                 // 6291456 bf16
  short* wob   = wqkv + 6291456;               // 4194304 bf16
  short* keysb = wob + 4194304;                // 2097152 bf16
  short* valsT = keysb + 2097152;              // 2097152 bf16 (V^T permuted)
  short* aout  = valsT + 2097152;              // 4194304 bf16
  float* qkv   = (float*)(aout + 4194304);     // 6291456 f32; total ~68 MB

  dim3 blk(256);

  f32_to_bf16<<<2048, blk, 0, stream>>>(x,  xb,   4194304);
  f32_to_bf16<<<2048, blk, 0, stream>>>(Wq, wqkv, 4194304);
  f32_to_bf16<<<512,  blk, 0, stream>>>(Wk, wqkv + 4194304, 1048576);
  f32_to_bf16<<<512,  blk, 0, stream>>>(Wv, wqkv + 5242880, 1048576);
  f32_to_bf16<<<2048, blk, 0, stream>>>(Wo, wob, 4194304);

  // zero split-K accumulators (ws + out are poisoned before every launch)
  zero_f32<<<6144, blk, 0, stream>>>((float4*)qkv, 1572864);
  zero_f32<<<4096, blk, 0, stream>>>((float4*)out, 1048576);

  // old-cache halves (independent of x)
  copy_cache_k<<<512, blk, 0, stream>>>(cache_k, keysb);
  vT_old<<<256, blk, 0, stream>>>(cache_v, valsT);

  // fused QKV projection, split-K=2: [2048,2048] @ [3072,2048]^T
  gemm_bf16_sk<<<dim3(NQKV / 128, (B * S) / 128, 2), blk, 0, stream>>>(xb, wqkv, qkv, B * S, NQKV, E);

  // RoPE-K + new KV halves (RoPE-Q is folded into attn_mfma)
  rope_k<<<(B * S * KVH * 32) / 256, blk, 0, stream>>>(qkv, cosb, sinb, keysb);
  vT_new<<<256, blk, 0, stream>>>(qkv, valsT);

  // attention -> bf16 (B,S,E)
  attn_mfma<<<B * H * (S / 64), blk, 0, stream>>>(qkv, cosb, sinb, keysb, valsT, aout);

  // output projection, split-K=2 -> f32 out
  gemm_bf16_sk<<<dim3(E / 128, (B * S) / 128, 2), blk, 0, stream>>>(aout, wob, out, B * S, E, E);
}

// Round 7
// 284.383 us; speedup vs baseline: 2.0624x; 1.1715x over previous
//
#include <hip/hip_runtime.h>
#include <cstddef>

#define B   2
#define S   1024
#define PP  1024          // start_pos
#define CTX 2048
#define E   2048
#define H   32
#define KVH 8
#define HD  64
#define GQ  4             // H / KVH
#define NQKV 3072         // E + 2*KVH*HD

typedef short s4v  __attribute__((ext_vector_type(4)));
typedef short s8v  __attribute__((ext_vector_type(8)));
typedef float f4v  __attribute__((ext_vector_type(4)));

__device__ __forceinline__ short f2bf(float f) {   // RNE f32 -> bf16
  union { float f; unsigned u; } v; v.f = f;
  unsigned r = v.u + 0x7fffu + ((v.u >> 16) & 1u);
  return (short)(r >> 16);
}
__device__ __forceinline__ float bf2f(short h) {
  union { unsigned u; float f; } v; v.u = ((unsigned)(unsigned short)h) << 16;
  return v.f;
}

__device__ __forceinline__ void gl_lds16(const void* g, void* l) {
  // async 16B/lane global->LDS; LDS dest = wave-uniform base + lane*16
  __builtin_amdgcn_global_load_lds((const __attribute__((address_space(1))) unsigned*)g,
                                   (__attribute__((address_space(3))) unsigned*)l, 16, 0, 0);
}

// ---------------------------------------------------------------------------
// prep: all f32->bf16 converts + cache_k copy + V^T(old) + zero(out).
// Grid partitioned by blockIdx.x:
//   [0,2048) x | [2048,4096) Wq | [4096,4608) Wk | [4608,5120) Wv
//   [5120,7168) Wo | [7168,7680) cache_k | [7680,7936) vT_old | [7936,8960) zero out
// ---------------------------------------------------------------------------
__global__ __launch_bounds__(256) void prep(const float* __restrict__ x,
                                            const float* __restrict__ Wq,
                                            const float* __restrict__ Wk,
                                            const float* __restrict__ Wv,
                                            const float* __restrict__ Wo,
                                            const float* __restrict__ ck,
                                            const float* __restrict__ cv,
                                            short* __restrict__ xb,
                                            short* __restrict__ wqkv,
                                            short* __restrict__ wob,
                                            short* __restrict__ keys,
                                            short* __restrict__ vt,
                                            float4* __restrict__ outz) {
  __shared__ short Ts[64][72];
  const int blk = blockIdx.x, tid = threadIdx.x;
  if (blk < 7168) {
    const float* s; short* d; int base;
    if (blk < 2048)      { s = x;  d = xb;             base = blk; }
    else if (blk < 4096) { s = Wq; d = wqkv;           base = blk - 2048; }
    else if (blk < 4608) { s = Wk; d = wqkv + 4194304; base = blk - 4096; }
    else if (blk < 5120) { s = Wv; d = wqkv + 5242880; base = blk - 4608; }
    else                 { s = Wo; d = wob;            base = blk - 5120; }
    int i = (base * 256 + tid) * 8;
    float4 a = *(const float4*)&s[i];
    float4 b = *(const float4*)&s[i + 4];
    s8v o;
    o[0]=f2bf(a.x); o[1]=f2bf(a.y); o[2]=f2bf(a.z); o[3]=f2bf(a.w);
    o[4]=f2bf(b.x); o[5]=f2bf(b.y); o[6]=f2bf(b.z); o[7]=f2bf(b.w);
    *(s8v*)&d[i] = o;
  } else if (blk < 7680) {
    // cache_k f32 [0,PP) -> bf16 keys
    int idx = (blk - 7168) * 256 + tid;
    int bkv = idx >> 13;
    int rem = idx & 8191;
    size_t off = (size_t)bkv * (CTX * HD) + (size_t)rem * 8;
    float4 a = *(const float4*)&ck[off];
    float4 b = *(const float4*)&ck[off + 4];
    s8v o;
    o[0]=f2bf(a.x); o[1]=f2bf(a.y); o[2]=f2bf(a.z); o[3]=f2bf(a.w);
    o[4]=f2bf(b.x); o[5]=f2bf(b.y); o[6]=f2bf(b.z); o[7]=f2bf(b.w);
    *(s8v*)&keys[off] = o;
  } else if (blk < 7936) {
    // cache_v [0,PP) -> valsT (permuted key order within 64-blocks)
    const int blk2 = blk - 7680;              // B*KVH*(PP/64) = 256
    const int bkv = blk2 >> 4;
    const int p0  = (blk2 & 15) * 64;
    const float* src = cv + (size_t)bkv * CTX * HD + (size_t)p0 * HD;
    {
      int dq = tid & 15, kb = tid >> 4;
      float4 vv[4];
#pragma unroll
      for (int i = 0; i < 4; i++)
        vv[i] = *(const float4*)&src[(size_t)(kb * 4 + i) * HD + dq * 4];
#pragma unroll
      for (int j = 0; j < 4; j++) {
        s4v p;
        p[0]=f2bf(((const float*)&vv[0])[j]); p[1]=f2bf(((const float*)&vv[1])[j]);
        p[2]=f2bf(((const float*)&vv[2])[j]); p[3]=f2bf(((const float*)&vv[3])[j]);
        *(s4v*)&Ts[dq * 4 + j][kb * 4] = p;
      }
    }
    __syncthreads();
    {
      int d = tid >> 2, c = tid & 3;
      short* dst = vt + ((size_t)bkv * HD + d) * CTX + p0 + (c >> 1) * 32 + (c & 1) * 4;
#pragma unroll
      for (int j = 0; j < 4; j++) {
        s4v q4 = *(const s4v*)&Ts[d][c * 16 + j * 4];
        *(s4v*)&dst[j * 8] = q4;
      }
    }
  } else {
    // zero f32 out (4,194,304 floats) for O-proj split-K atomics
    int i0 = (blk - 7936) * 1024 + tid * 4;
#pragma unroll
    for (int j = 0; j < 4; j++) outz[i0 + j] = make_float4(0.f, 0.f, 0.f, 0.f);
  }
}

// ---------------------------------------------------------------------------
// QKV GEMM, no split-K, fused epilogue: writes q (bf16, B,S,E), k_tmp (bf16,
// B,S,512, un-roped), and V directly into permuted valsT layout.
// Within-64 row index i = mt*16+g*4+r maps to perm (mt>>1)*32+(mt&1)*4+g*8+r
// (consecutive in r -> s4v stores).
// ---------------------------------------------------------------------------
__global__ __launch_bounds__(256) void qkv_gemm(const short* __restrict__ A,
                                                const short* __restrict__ Bw,
                                                short* __restrict__ qb,
                                                short* __restrict__ ktmp,
                                                short* __restrict__ vt) {
  __shared__ short As[4096];
  __shared__ short Bs[4096];
  const int tid  = threadIdx.x;
  const int wv   = tid >> 6, lane = tid & 63;
  const int wm   = wv & 1, wn = wv >> 1;
  const int n16  = lane & 15, g = lane >> 4;
  const int m0   = blockIdx.y * 128, n0 = blockIdx.x * 128;
  const int K = 2048;

  const int s0 = tid, s1 = 256 + tid;
  const int r0 = s0 >> 2, c0 = ((s0 & 3) ^ ((r0 >> 1) & 3)) * 8;
  const int r1 = s1 >> 2, c1 = ((s1 & 3) ^ ((r1 >> 1) & 3)) * 8;
  const short* pA0 = A + (size_t)(m0 + r0) * K + c0;
  const short* pA1 = A + (size_t)(m0 + r1) * K + c1;
  const short* pB0 = Bw + (size_t)(n0 + r0) * K + c0;
  const short* pB1 = Bw + (size_t)(n0 + r1) * K + c1;
  short* lA0 = As + (wv * 64) * 8;
  short* lA1 = As + (256 + wv * 64) * 8;
  short* lB0 = Bs + (wv * 64) * 8;
  short* lB1 = Bs + (256 + wv * 64) * 8;

  const int xv = (g ^ ((n16 >> 1) & 3)) * 8;

  f4v acc[4][4] = {};
  for (int k0 = 0; k0 < K; k0 += 32) {
    __syncthreads();
    gl_lds16(pA0, lA0); gl_lds16(pA1, lA1);
    gl_lds16(pB0, lB0); gl_lds16(pB1, lB1);
    pA0 += 32; pA1 += 32; pB0 += 32; pB1 += 32;
    __syncthreads();

    s8v af[4], bf[4];
#pragma unroll
    for (int mt = 0; mt < 4; mt++)
      af[mt] = *(const s8v*)&As[(wm * 64 + mt * 16 + n16) * 32 + xv];
#pragma unroll
    for (int nt = 0; nt < 4; nt++)
      bf[nt] = *(const s8v*)&Bs[(wn * 64 + nt * 16 + n16) * 32 + xv];
#pragma unroll
    for (int mt = 0; mt < 4; mt++)
#pragma unroll
      for (int nt = 0; nt < 4; nt++)
        acc[mt][nt] = __builtin_amdgcn_mfma_f32_16x16x32_bf16(af[mt], bf[nt], acc[mt][nt], 0, 0, 0);
  }

  const int rowb = m0 + wm * 64 + g * 4;
  const int colb = n0 + wn * 64 + n16;
  if (n0 < 2048) {
    // Q region -> qb (B,S,E) bf16
#pragma unroll
    for (int mt = 0; mt < 4; mt++)
#pragma unroll
      for (int nt = 0; nt < 4; nt++) {
        size_t base = (size_t)(rowb + mt * 16) * E + colb + nt * 16;
#pragma unroll
        for (int r = 0; r < 4; r++)
          qb[base + (size_t)r * E] = f2bf(acc[mt][nt][r]);
      }
  } else if (n0 < 2560) {
    // K region -> ktmp (B,S,512) bf16 (RoPE applied by rope_kb)
#pragma unroll
    for (int mt = 0; mt < 4; mt++)
#pragma unroll
      for (int nt = 0; nt < 4; nt++) {
        size_t base = (size_t)(rowb + mt * 16) * 512 + colb - 2048 + nt * 16;
#pragma unroll
        for (int r = 0; r < 4; r++)
          ktmp[base + (size_t)r * 512] = f2bf(acc[mt][nt][r]);
      }
  } else {
    // V region -> valsT[(bkv*HD+d)*CTX + PP + perm(s)]
    const int b    = m0 >> 10;
    const int head = ((n0 - 2560) >> 6) + wn;
    const int sbase = (m0 - (b << 10)) + wm * 64;   // multiple of 64
    const size_t vrowb = (size_t)(b * KVH + head) * HD;
#pragma unroll
    for (int mt = 0; mt < 4; mt++) {
      const int pos = PP + sbase + ((mt >> 1) << 5) + ((mt & 1) << 2) + (g << 3);
#pragma unroll
      for (int nt = 0; nt < 4; nt++) {
        const int d = nt * 16 + n16;
        s4v o;
        o[0] = f2bf(acc[mt][nt][0]); o[1] = f2bf(acc[mt][nt][1]);
        o[2] = f2bf(acc[mt][nt][2]); o[3] = f2bf(acc[mt][nt][3]);
        *(s4v*)&vt[(vrowb + d) * CTX + pos] = o;
      }
    }
  }
}

// ---------------------------------------------------------------------------
// bf16 MFMA GEMM, split-K=2, atomic f32 accumulate (for O-proj).
// ---------------------------------------------------------------------------
__global__ __launch_bounds__(256) void gemm_bf16_sk(const short* __restrict__ A,
                                                    const short* __restrict__ Bw,
                                                    float* __restrict__ C,
                                                    int M, int N, int K) {
  __shared__ short As[4096];
  __shared__ short Bs[4096];
  const int tid  = threadIdx.x;
  const int wv   = tid >> 6, lane = tid & 63;
  const int wm   = wv & 1, wn = wv >> 1;
  const int n16  = lane & 15, g = lane >> 4;
  const int m0   = blockIdx.y * 128, n0 = blockIdx.x * 128;
  const int kh   = K >> 1;
  const int kbeg = blockIdx.z * kh;

  const int s0 = tid, s1 = 256 + tid;
  const int r0 = s0 >> 2, c0 = ((s0 & 3) ^ ((r0 >> 1) & 3)) * 8;
  const int r1 = s1 >> 2, c1 = ((s1 & 3) ^ ((r1 >> 1) & 3)) * 8;
  const short* pA0 = A + (size_t)(m0 + r0) * K + kbeg + c0;
  const short* pA1 = A + (size_t)(m0 + r1) * K + kbeg + c1;
  const short* pB0 = Bw + (size_t)(n0 + r0) * K + kbeg + c0;
  const short* pB1 = Bw + (size_t)(n0 + r1) * K + kbeg + c1;
  short* lA0 = As + (wv * 64) * 8;
  short* lA1 = As + (256 + wv * 64) * 8;
  short* lB0 = Bs + (wv * 64) * 8;
  short* lB1 = Bs + (256 + wv * 64) * 8;

  const int xv = (g ^ ((n16 >> 1) & 3)) * 8;

  f4v acc[4][4] = {};
  for (int k0 = 0; k0 < kh; k0 += 32) {
    __syncthreads();
    gl_lds16(pA0, lA0); gl_lds16(pA1, lA1);
    gl_lds16(pB0, lB0); gl_lds16(pB1, lB1);
    pA0 += 32; pA1 += 32; pB0 += 32; pB1 += 32;
    __syncthreads();

    s8v af[4], bf[4];
#pragma unroll
    for (int mt = 0; mt < 4; mt++)
      af[mt] = *(const s8v*)&As[(wm * 64 + mt * 16 + n16) * 32 + xv];
#pragma unroll
    for (int nt = 0; nt < 4; nt++)
      bf[nt] = *(const s8v*)&Bs[(wn * 64 + nt * 16 + n16) * 32 + xv];
#pragma unroll
    for (int mt = 0; mt < 4; mt++)
#pragma unroll
      for (int nt = 0; nt < 4; nt++)
        acc[mt][nt] = __builtin_amdgcn_mfma_f32_16x16x32_bf16(af[mt], bf[nt], acc[mt][nt], 0, 0, 0);
  }

#pragma unroll
  for (int mt = 0; mt < 4; mt++)
#pragma unroll
    for (int nt = 0; nt < 4; nt++) {
      size_t base = (size_t)(m0 + wm * 64 + mt * 16 + g * 4) * N + n0 + wn * 64 + nt * 16 + n16;
#pragma unroll
      for (int r = 0; r < 4; r++)
        unsafeAtomicAdd(&C[base + (size_t)r * N], acc[mt][nt][r]);
    }
}

// ---------------------------------------------------------------------------
// RoPE on bf16 ktmp + scatter into keys at pos PP+s.
// ---------------------------------------------------------------------------
__global__ __launch_bounds__(256) void rope_kb(const short* __restrict__ ktmp,
                                               const float* __restrict__ cosb,
                                               const float* __restrict__ sinb,
                                               short* __restrict__ keys) {
  int idx = blockIdx.x * 256 + threadIdx.x;   // B*S*KVH*32
  int d = idx & 31;
  int kv = (idx >> 5) & (KVH - 1);
  int s = (idx >> 8) & (S - 1);
  int b = idx >> 18;
  size_t row = (size_t)b * S + s;
  float c = cosb[row * HD + d];
  float sn = sinb[row * HD + d];
  float k1 = bf2f(ktmp[row * 512 + kv * 64 + d]);
  float k2 = bf2f(ktmp[row * 512 + kv * 64 + d + 32]);
  size_t drow = (((size_t)b * KVH + kv) * CTX + PP + s) * HD;
  keys[drow + d]      = f2bf(k1 * c - k2 * sn);
  keys[drow + d + 32] = f2bf(k2 * c + k1 * sn);
}

// ---------------------------------------------------------------------------
// MFMA flash attention: fixed-max exp2 softmax, gl_lds-staged K & V^T with
// XOR chunk swizzle (chunk (lane&7)^row; frag slot (g^(n&7))*8, hi ^32 —
// the gemm-verified 0-conflict pattern), register P^T, RoPE-Q fused (bf16 in).
// ---------------------------------------------------------------------------
__global__ __launch_bounds__(256) void attn_mfma(const short* __restrict__ qb,
                                                 const float* __restrict__ cosb,
                                                 const float* __restrict__ sinb,
                                                 const short* __restrict__ keys,
                                                 const short* __restrict__ valsT,
                                                 short* __restrict__ attn) {
  __shared__ short Ks[4096];    // K tile [key][dim] 64x64, chunk-swizzled
  __shared__ short VTs[4096];   // V^T tile [dim][permuted key], chunk-swizzled

  const int sblk = 15 - (blockIdx.x & 15);     // long blocks first
  const int h    = (blockIdx.x >> 4) & (H - 1);
  const int b    = blockIdx.x >> 9;
  const int kv   = h >> 2;
  const int sq0  = sblk * 64;
  const int kend = PP + sq0 + 64;

  const int tid  = threadIdx.x;
  const int w    = tid >> 6;
  const int lane = tid & 63;
  const int n    = lane & 15;
  const int g    = lane >> 4;

  const short* kbase = keys  + ((size_t)b * KVH + kv) * CTX * HD;
  const short* vtb   = valsT + ((size_t)b * KVH + kv) * (size_t)HD * CTX;

  // ---- Q frags: bf16 in, RoPE fused, scale = 0.125*log2(e) ----
  union { s4v h4[2]; s8v v; } qlo, qhi;
  {
    const size_t row = (size_t)b * S + sq0 + w * 16 + n;
    const short* qrow = qb + row * E + h * 64;
    const float* crow = cosb + row * HD;
    const float* srow = sinb + row * HD;
    const float SC = 0.18033688011112042f;   // 0.125 * log2(e)
    s8v q0 = *(const s8v*)&qrow[g * 8];
    s8v q1 = *(const s8v*)&qrow[32 + g * 8];
    float cc[8], ss[8];
    *(float4*)&cc[0] = *(const float4*)&crow[g * 8];
    *(float4*)&cc[4] = *(const float4*)&crow[g * 8 + 4];
    *(float4*)&ss[0] = *(const float4*)&srow[g * 8];
    *(float4*)&ss[4] = *(const float4*)&srow[g * 8 + 4];
#pragma unroll
    for (int j = 0; j < 8; j++) {
      float fl = bf2f(q0[j]), fh = bf2f(q1[j]);
      qlo.v[j] = f2bf((fl * cc[j] - fh * ss[j]) * SC);
      qhi.v[j] = f2bf((fh * cc[j] + fl * ss[j]) * SC);
    }
  }

  f4v O[4] = {{0,0,0,0},{0,0,0,0},{0,0,0,0},{0,0,0,0}};
  float l = 0.f;
  const int qp     = PP + sq0 + w * 16 + n;    // this lane's query position
  const int qmin_w = PP + sq0 + w * 16;        // wave's min query position

  // gl_lds staging: wave w stages rows w*8..w*8+7 (+32) of each 64x64 tile;
  // lane: row = w*8 + (lane>>3), chunk slot = lane&7 holds global chunk slot^row
  const int lrow = lane >> 3;
  const int sw   = (lane & 7) ^ lrow;
  const short* kg0 = kbase + (size_t)(w * 8 + lrow) * HD + sw * 8;
  const short* kg1 = kg0 + 32 * HD;
  const short* vg0 = vtb + (size_t)(w * 8 + lrow) * CTX + sw * 8;
  const short* vg1 = vg0 + (size_t)32 * CTX;
  short* kl0 = Ks + w * 512;
  short* kl1 = Ks + 2048 + w * 512;
  short* vl0 = VTs + w * 512;
  short* vl1 = VTs + 2048 + w * 512;

  const int xsl = (g ^ (n & 7)) * 8;   // swizzled frag slot (lo); hi = ^32

  for (int k0 = 0; k0 < kend; k0 += 64) {
    __syncthreads();
    gl_lds16(kg0 + (size_t)k0 * HD, kl0);
    gl_lds16(kg1 + (size_t)k0 * HD, kl1);
    gl_lds16(vg0 + k0, vl0);
    gl_lds16(vg1 + k0, vl1);
    __syncthreads();

    if (k0 >= qmin_w + 16) continue;   // wave's K-range done (barriers aligned)

    // ---- S^T = K_tile @ Q^T (scores in log2 units) ----
    f4v sc[4];
#pragma unroll
    for (int st = 0; st < 4; st++) {
      const short* krow = &Ks[(st * 16 + n) * 64];
      s8v alo = *(const s8v*)(krow + xsl);
      s8v ahi = *(const s8v*)(krow + (xsl ^ 32));
      f4v z = {0.f, 0.f, 0.f, 0.f};
      z = __builtin_amdgcn_mfma_f32_16x16x32_bf16(alo, qlo.v, z, 0, 0, 0);
      sc[st] = __builtin_amdgcn_mfma_f32_16x16x32_bf16(ahi, qhi.v, z, 0, 0, 0);
    }

    // ---- causal mask near diagonal ----
    if (k0 + 63 > qmin_w) {
#pragma unroll
      for (int st = 0; st < 4; st++)
#pragma unroll
        for (int r = 0; r < 4; r++) {
          int kpos = k0 + st * 16 + g * 4 + r;
          if (kpos > qp) sc[st][r] = -3e38f;
        }
    }

    // ---- fixed-max exp2; P^T packed straight into PV B-operand regs ----
    union { s4v h4[2]; s8v v; } pb0, pb1;
#pragma unroll
    for (int st = 0; st < 4; st++) {
      s4v pw;
#pragma unroll
      for (int r = 0; r < 4; r++) {
        float e = __builtin_amdgcn_exp2f(sc[st][r] - 16.f);
        l += e;
        pw[r] = f2bf(e);
      }
      if (st < 2) pb0.h4[st] = pw; else pb1.h4[st - 2] = pw;
    }

    // ---- O^T += V^T @ P ----
#pragma unroll
    for (int dg = 0; dg < 4; dg++) {
      const short* vr = &VTs[(dg * 16 + n) * 64];
      s8v va = *(const s8v*)(vr + xsl);
      s8v vb = *(const s8v*)(vr + (xsl ^ 32));
      O[dg] = __builtin_amdgcn_mfma_f32_16x16x32_bf16(va, pb0.v, O[dg], 0, 0, 0);
      O[dg] = __builtin_amdgcn_mfma_f32_16x16x32_bf16(vb, pb1.v, O[dg], 0, 0, 0);
    }
  }

  // ---- reduce l across 4 g-lanes per query, normalize, store ----
  l += __shfl_xor(l, 16);
  l += __shfl_xor(l, 32);
  const float rl = 1.f / l;
  short* orow = attn + ((size_t)b * S + sq0 + w * 16 + n) * E + h * 64;
#pragma unroll
  for (int dg = 0; dg < 4; dg++) {
    s4v o;
    o[0] = f2bf(O[dg][0] * rl); o[1] = f2bf(O[dg][1] * rl);
    o[2] = f2bf(O[dg][2] * rl); o[3] = f2bf(O[dg][3] * rl);
    *(s4v*)&orow[dg * 16 + g * 4] = o;
  }
}

// ---------------------------------------------------------------------------
extern "C" void kernel_launch(void* const* d_in, const int* in_sizes, int n_in,
                              void* d_out, int out_size, void* d_ws, size_t ws_size,
                              hipStream_t stream) {
  const float* x       = (const float*)d_in[0];
  const float* cosb    = (const float*)d_in[1];
  const float* sinb    = (const float*)d_in[2];
  const float* cache_k = (const float*)d_in[4];
  const float* cache_v = (const float*)d_in[5];
  const float* Wq      = (const float*)d_in[6];
  const float* Wk      = (const float*)d_in[7];
  const float* Wv      = (const float*)d_in[8];
  const float* Wo      = (const float*)d_in[9];
  float* out = (float*)d_out;

  short* xb    = (short*)d_ws;                 // 4,194,304
  short* wqkv  = xb + 4194304;                 // 6,291,456
  short* wob   = wqkv + 6291456;               // 4,194,304
  short* keysb = wob + 4194304;                // 2,097,152
  short* valsT = keysb + 2097152;              // 2,097,152 (permuted V^T)
  short* aout  = valsT + 2097152;              // 4,194,304
  short* qb    = aout + 4194304;               // 4,194,304
  short* ktmp  = qb + 4194304;                 // 1,048,576  (~57 MB total)

  dim3 blk(256);

  // 1) all converts + cache_k + vT_old + zero(out)
  prep<<<8960, blk, 0, stream>>>(x, Wq, Wk, Wv, Wo, cache_k, cache_v,
                                 xb, wqkv, wob, keysb, valsT, (float4*)out);

  // 2) fused QKV projection: q bf16 / ktmp bf16 / valsT direct
  qkv_gemm<<<dim3(NQKV / 128, (B * S) / 128), blk, 0, stream>>>(xb, wqkv, qb, ktmp, valsT);

  // 3) RoPE-K -> keys [PP, CTX)
  rope_kb<<<(B * S * KVH * 32) / 256, blk, 0, stream>>>(ktmp, cosb, sinb, keysb);

  // 4) attention -> bf16 (B,S,E)
  attn_mfma<<<B * H * (S / 64), blk, 0, stream>>>(qb, cosb, sinb, keysb, valsT, aout);

  // 5) output projection, split-K=2 -> f32 out (zeroed in prep)
  gemm_bf16_sk<<<dim3(E / 128, (B * S) / 128, 2), blk, 0, stream>>>(aout, wob, out, B * S, E, E);
}